// Round 3
// baseline (576.790 us; speedup 1.0000x reference)
//
#include <hip/hip_runtime.h>

// NodeNetwork fused kernel (f32, VALU): 64 nodes/block, 256 threads (4 waves).
// Wave w computes output j-slice w for all 64 nodes -> weight loads wave-uniform.
// Mailbox streaming (80% of HBM bytes) is fused into branch-1 phase 2 so loads
// stay outstanding under the FMA stream (convoy fix: HBM busy during compute).
constexpr int NB = 64;
constexpr int THREADS = 256;
constexpr int X1S = 132;   // x1 LDS row stride (slot8 = (n+k4)&7 -> uniform, ~conflict-free b128)
constexpr int H1S = 100;   // h1 LDS row stride, aliases x1 region
constexpr int X2S = 68;    // x2/h2 LDS row stride

typedef float vf4 __attribute__((ext_vector_type(4)));

__device__ __forceinline__ float fast_tanh(float x) {
    // tanh(x) = 1 - 2/(exp(2x)+1); v_exp + v_rcp, abs err ~1e-6, saturates to +-1.
    float e = __expf(2.0f * x);
    return 1.0f - 2.0f * __builtin_amdgcn_rcpf(e + 1.0f);
}

__global__ __launch_bounds__(THREADS, 3) void node_net_kernel(
    const float* __restrict__ feat, const float* __restrict__ hid,
    const float* __restrict__ mail,
    const float* __restrict__ w1a, const float* __restrict__ b1a,
    const float* __restrict__ w1b, const float* __restrict__ b1b,
    const float* __restrict__ w2a, const float* __restrict__ b2a,
    const float* __restrict__ w2b, const float* __restrict__ b2b,
    float* __restrict__ out)
{
    __shared__ float ldsA[NB * X1S];   // x1, later h1
    __shared__ float ldsB[NB * X2S];   // x2, later h2
    __shared__ float ldsS[NB * 4];     // per-sub partial sumsq

    const int t  = threadIdx.x;
    const int n0 = blockIdx.x * NB;
    const int c4 = t & 15;             // float4 column 0..15
    const int nb = t >> 4;             // node base 0..15; this thread owns nodes nb+16i

    // ---------- Phase 1a: stage x1 = [feat|hid] ----------
    #pragma unroll
    for (int i = 0; i < 4; ++i) {
        int n = nb + 16 * i;
        float4 f = reinterpret_cast<const float4*>(feat)[(size_t)(n0 + n) * 16 + c4];
        float4 h = reinterpret_cast<const float4*>(hid )[(size_t)(n0 + n) * 16 + c4];
        float4* dst = reinterpret_cast<float4*>(&ldsA[n * X1S]);
        dst[c4]      = f;
        dst[16 + c4] = h;
    }
    __syncthreads();

    const int node = t & 63;
    const int sub  = __builtin_amdgcn_readfirstlane(t >> 6);  // wave id 0..3, SGPR-uniform

    // ---------- Phase 2: h1 = relu(x1 @ w1a + b1a), j-slice of 24,
    //            FUSED with mailbox streaming (4 chunks x 16 float4 loads) ----------
    float acc1[24];
    {
        const float* b = b1a + sub * 24;
        #pragma unroll
        for (int j = 0; j < 24; ++j) acc1[j] = b[j];
    }
    float4 macc[4];
    {
        const float4* xr  = reinterpret_cast<const float4*>(&ldsA[node * X1S]);
        const float4* mb0 = reinterpret_cast<const float4*>(mail)
                          + (size_t)(n0 + nb) * 256 + c4;   // [N][16][64]: node stride 256 f4, d stride 16 f4

        #pragma unroll 1
        for (int c = 0; c < 4; ++c) {
            // issue this chunk's 16 loads (kept in flight under the FMAs below)
            float4 ld[4][4];
            #pragma unroll
            for (int i = 0; i < 4; ++i) {
                const float4* mi = mb0 + (size_t)i * 16 * 256 + (c * 4) * 16;
                #pragma unroll
                for (int dd = 0; dd < 4; ++dd)
                    ld[i][dd] = mi[dd * 16];
            }
            // 8 of 32 k4-iterations of branch-1 layer A
            #pragma unroll
            for (int kk = 0; kk < 8; ++kk) {
                int k4 = c * 8 + kk;
                float4 x = xr[k4];
                const float* w0 = w1a + (k4 * 4) * 96 + sub * 24;
                #pragma unroll
                for (int j = 0; j < 24; ++j) acc1[j] = fmaf(x.x, w0[j],       acc1[j]);
                #pragma unroll
                for (int j = 0; j < 24; ++j) acc1[j] = fmaf(x.y, w0[96 + j],  acc1[j]);
                #pragma unroll
                for (int j = 0; j < 24; ++j) acc1[j] = fmaf(x.z, w0[192 + j], acc1[j]);
                #pragma unroll
                for (int j = 0; j < 24; ++j) acc1[j] = fmaf(x.w, w0[288 + j], acc1[j]);
            }
            // fold chunk into running mailbox sums
            if (c == 0) {
                #pragma unroll
                for (int i = 0; i < 4; ++i)
                    macc[i] = (ld[i][0] + ld[i][1]) + (ld[i][2] + ld[i][3]);
            } else {
                #pragma unroll
                for (int i = 0; i < 4; ++i)
                    macc[i] += (ld[i][0] + ld[i][1]) + (ld[i][2] + ld[i][3]);
            }
        }
    }
    // write x2 rows (nobody reads ldsB until after the next barriers)
    #pragma unroll
    for (int i = 0; i < 4; ++i)
        *reinterpret_cast<float4*>(&ldsB[(nb + 16 * i) * X2S + c4 * 4]) = macc[i];

    __syncthreads();                     // all x1 reads done; reuse ldsA for h1
    {
        float4* hrow = reinterpret_cast<float4*>(&ldsA[node * H1S + sub * 24]);
        #pragma unroll
        for (int j4 = 0; j4 < 6; ++j4) {
            float4 v;
            v.x = fmaxf(acc1[j4*4+0], 0.f);
            v.y = fmaxf(acc1[j4*4+1], 0.f);
            v.z = fmaxf(acc1[j4*4+2], 0.f);
            v.w = fmaxf(acc1[j4*4+3], 0.f);
            hrow[j4] = v;
        }
    }
    __syncthreads();

    // ---------- Phase 3: r1 = tanh(h1 @ w1b + b1b), j-slice of 16 ----------
    float r1v[16];
    {
        float acc[16];
        const float* b = b1b + sub * 16;
        #pragma unroll
        for (int j = 0; j < 16; ++j) acc[j] = b[j];
        const float4* hr = reinterpret_cast<const float4*>(&ldsA[node * H1S]);
        #pragma unroll 2
        for (int k4 = 0; k4 < 24; ++k4) {
            float4 x = hr[k4];
            const float* w0 = w1b + (k4 * 4) * 64 + sub * 16;
            #pragma unroll
            for (int j = 0; j < 16; ++j) acc[j] = fmaf(x.x, w0[j],       acc[j]);
            #pragma unroll
            for (int j = 0; j < 16; ++j) acc[j] = fmaf(x.y, w0[64 + j],  acc[j]);
            #pragma unroll
            for (int j = 0; j < 16; ++j) acc[j] = fmaf(x.z, w0[128 + j], acc[j]);
            #pragma unroll
            for (int j = 0; j < 16; ++j) acc[j] = fmaf(x.w, w0[192 + j], acc[j]);
        }
        #pragma unroll
        for (int j = 0; j < 16; ++j) r1v[j] = fast_tanh(acc[j]);
    }

    // ---------- Phase 4: h2 = relu(x2 @ w2a + b2a), j-slice of 16 ----------
    float h2v[16];
    {
        float acc[16];
        const float* b = b2a + sub * 16;
        #pragma unroll
        for (int j = 0; j < 16; ++j) acc[j] = b[j];
        const float4* xr = reinterpret_cast<const float4*>(&ldsB[node * X2S]);
        #pragma unroll 2
        for (int k4 = 0; k4 < 16; ++k4) {
            float4 x = xr[k4];
            const float* w0 = w2a + (k4 * 4) * 64 + sub * 16;
            #pragma unroll
            for (int j = 0; j < 16; ++j) acc[j] = fmaf(x.x, w0[j],       acc[j]);
            #pragma unroll
            for (int j = 0; j < 16; ++j) acc[j] = fmaf(x.y, w0[64 + j],  acc[j]);
            #pragma unroll
            for (int j = 0; j < 16; ++j) acc[j] = fmaf(x.z, w0[128 + j], acc[j]);
            #pragma unroll
            for (int j = 0; j < 16; ++j) acc[j] = fmaf(x.w, w0[192 + j], acc[j]);
        }
        #pragma unroll
        for (int j = 0; j < 16; ++j) h2v[j] = fmaxf(acc[j], 0.f);
    }
    __syncthreads();                     // all x2 reads done; reuse ldsB for h2
    {
        float4* hrow = reinterpret_cast<float4*>(&ldsB[node * X2S + sub * 16]);
        hrow[0] = make_float4(h2v[0], h2v[1], h2v[2], h2v[3]);
        hrow[1] = make_float4(h2v[4], h2v[5], h2v[6], h2v[7]);
        hrow[2] = make_float4(h2v[8], h2v[9], h2v[10], h2v[11]);
        hrow[3] = make_float4(h2v[12], h2v[13], h2v[14], h2v[15]);
    }
    __syncthreads();

    // ---------- Phase 5: r2 = tanh(h2 @ w2b + b2b), j-slice of 16 ----------
    float r2v[16];
    {
        float acc[16];
        const float* b = b2b + sub * 16;
        #pragma unroll
        for (int j = 0; j < 16; ++j) acc[j] = b[j];
        const float4* hr = reinterpret_cast<const float4*>(&ldsB[node * X2S]);
        #pragma unroll 2
        for (int k4 = 0; k4 < 16; ++k4) {
            float4 x = hr[k4];
            const float* w0 = w2b + (k4 * 4) * 64 + sub * 16;
            #pragma unroll
            for (int j = 0; j < 16; ++j) acc[j] = fmaf(x.x, w0[j],       acc[j]);
            #pragma unroll
            for (int j = 0; j < 16; ++j) acc[j] = fmaf(x.y, w0[64 + j],  acc[j]);
            #pragma unroll
            for (int j = 0; j < 16; ++j) acc[j] = fmaf(x.z, w0[128 + j], acc[j]);
            #pragma unroll
            for (int j = 0; j < 16; ++j) acc[j] = fmaf(x.w, w0[192 + j], acc[j]);
        }
        #pragma unroll
        for (int j = 0; j < 16; ++j) r2v[j] = fast_tanh(acc[j]);
    }

    // ---------- Phase 6: row L2 norm + write ----------
    float s = 0.f;
    #pragma unroll
    for (int j = 0; j < 16; ++j) s = fmaf(r1v[j], r1v[j], s);
    #pragma unroll
    for (int j = 0; j < 16; ++j) s = fmaf(r2v[j], r2v[j], s);
    ldsS[node * 4 + sub] = s;
    __syncthreads();
    float4 sv = reinterpret_cast<const float4*>(ldsS)[node];
    float rn = rsqrtf(sv.x + sv.y + sv.z + sv.w);

    float* orow = out + (size_t)(n0 + node) * 128;
    float4* o1 = reinterpret_cast<float4*>(orow + sub * 16);
    float4* o2 = reinterpret_cast<float4*>(orow + 64 + sub * 16);
    #pragma unroll
    for (int j4 = 0; j4 < 4; ++j4) {
        o1[j4] = make_float4(r1v[j4*4+0]*rn, r1v[j4*4+1]*rn, r1v[j4*4+2]*rn, r1v[j4*4+3]*rn);
        o2[j4] = make_float4(r2v[j4*4+0]*rn, r2v[j4*4+1]*rn, r2v[j4*4+2]*rn, r2v[j4*4+3]*rn);
    }
}

extern "C" void kernel_launch(void* const* d_in, const int* in_sizes, int n_in,
                              void* d_out, int out_size, void* d_ws, size_t ws_size,
                              hipStream_t stream) {
    const float* feat = (const float*)d_in[0];
    const float* hid  = (const float*)d_in[1];
    const float* mail = (const float*)d_in[2];
    const float* w1a  = (const float*)d_in[3];
    const float* b1a  = (const float*)d_in[4];
    const float* w1b  = (const float*)d_in[5];
    const float* b1b  = (const float*)d_in[6];
    const float* w2a  = (const float*)d_in[7];
    const float* b2a  = (const float*)d_in[8];
    const float* w2b  = (const float*)d_in[9];
    const float* b2b  = (const float*)d_in[10];
    float* out = (float*)d_out;

    const int N = in_sizes[0] / 64;          // 200000
    const int blocks = N / NB;               // 3125

    node_net_kernel<<<blocks, THREADS, 0, stream>>>(
        feat, hid, mail, w1a, b1a, w1b, b1b, w2a, b2a, w2b, b2b, out);
}

// Round 4
// 278.884 us; speedup vs baseline: 2.0682x; 2.0682x over previous
//
#include <hip/hip_runtime.h>

// NodeNetwork fused kernel (f32, VALU): 64 nodes/block, 256 threads (4 waves).
// R1 structure (proven 303us) + mailbox streaming embedded in phase 2 with
// sched_barrier-pinned 8-load batches so HBM stays busy under the FMA stream.
constexpr int NB = 64;
constexpr int THREADS = 256;
constexpr int X1S = 132;   // x1 LDS row stride: 33 f4, slot=(n+k4)&7 -> conflict-free b128
constexpr int H1S = 100;   // h1 LDS row stride: 25 f4, slot=(n+k4)&7 -> conflict-free
constexpr int X2S = 68;    // x2/h2 LDS row stride: 17 f4 -> conflict-free

__device__ __forceinline__ float fast_tanh(float x) {
    // tanh(x) = 1 - 2/(exp(2x)+1); v_exp+v_rcp, abs err ~1e-6, saturates to +-1.
    float e = __expf(2.0f * x);
    return 1.0f - 2.0f * __builtin_amdgcn_rcpf(e + 1.0f);
}

__global__ __launch_bounds__(THREADS) void node_net_kernel(
    const float* __restrict__ feat, const float* __restrict__ hid,
    const float* __restrict__ mail,
    const float* __restrict__ w1a, const float* __restrict__ b1a,
    const float* __restrict__ w1b, const float* __restrict__ b1b,
    const float* __restrict__ w2a, const float* __restrict__ b2a,
    const float* __restrict__ w2b, const float* __restrict__ b2b,
    float* __restrict__ out)
{
    __shared__ float ldsA[NB * X1S];   // x1, later h1
    __shared__ float ldsB[NB * X2S];   // x2, later h2
    __shared__ float ldsS[NB * 4];     // per-sub partial sumsq

    const int t  = threadIdx.x;
    const int n0 = blockIdx.x * NB;
    const int c4 = t & 15;             // float4 column 0..15
    const int nb = t >> 4;             // node base 0..15; owns nodes nb+16c for mailbox

    // ---------- Phase 1: stage x1 = [feat|hid] ----------
    #pragma unroll
    for (int i = 0; i < 4; ++i) {
        int n = nb + 16 * i;
        float4 f = reinterpret_cast<const float4*>(feat)[(size_t)(n0 + n) * 16 + c4];
        float4 g = reinterpret_cast<const float4*>(hid )[(size_t)(n0 + n) * 16 + c4];
        float4* dst = reinterpret_cast<float4*>(&ldsA[n * X1S]);
        dst[c4]      = f;
        dst[16 + c4] = g;
    }
    __syncthreads();

    const int node = t & 63;
    const int sub  = __builtin_amdgcn_readfirstlane(t >> 6);  // wave id 0..3, uniform

    // ---------- Phase 2: h1 = relu(x1 @ w1a + b1a), j-slice of 24,
    //            with mailbox streaming pinned under the FMA stream ----------
    float acc1[24];
    {
        const float* b = b1a + sub * 24;
        #pragma unroll
        for (int j = 0; j < 24; ++j) acc1[j] = b[j];
    }
    {
        const float4* xr  = reinterpret_cast<const float4*>(&ldsA[node * X1S]);
        const float4* mb0 = reinterpret_cast<const float4*>(mail)
                          + (size_t)(n0 + nb) * 256 + c4;  // [N][16][64]: node=256 f4, depth=16 f4

        #pragma unroll 1
        for (int c = 0; c < 4; ++c) {                      // chain c: node nb+16c
            const float4* chain = mb0 + (size_t)c * 4096;  // 16 nodes * 256 f4
            float4 m;
            #pragma unroll
            for (int half = 0; half < 2; ++half) {         // depths [8*half, 8*half+8)
                float4 cur[8];
                #pragma unroll
                for (int d = 0; d < 8; ++d)
                    cur[d] = chain[(half * 8 + d) * 16];
                __builtin_amdgcn_sched_barrier(0);         // pin: loads issued above
                // 4 k4-iterations (384 FMAs) run while the 8 loads are in flight
                #pragma unroll
                for (int kk = 0; kk < 4; ++kk) {
                    int k4 = (c * 2 + half) * 4 + kk;
                    float4 x = xr[k4];
                    const float* w0 = w1a + (k4 * 4) * 96 + sub * 24;
                    #pragma unroll
                    for (int j = 0; j < 24; ++j) acc1[j] = fmaf(x.x, w0[j],       acc1[j]);
                    #pragma unroll
                    for (int j = 0; j < 24; ++j) acc1[j] = fmaf(x.y, w0[96 + j],  acc1[j]);
                    #pragma unroll
                    for (int j = 0; j < 24; ++j) acc1[j] = fmaf(x.z, w0[192 + j], acc1[j]);
                    #pragma unroll
                    for (int j = 0; j < 24; ++j) acc1[j] = fmaf(x.w, w0[288 + j], acc1[j]);
                }
                __builtin_amdgcn_sched_barrier(0);         // pin: consume below FMAs
                float4 s = ((cur[0] + cur[1]) + (cur[2] + cur[3]))
                         + ((cur[4] + cur[5]) + (cur[6] + cur[7]));
                if (half == 0) m = s; else m += s;         // static (half unrolled)
            }
            // x2 row for node nb+16c done; ldsB untouched until after barrier 1
            *reinterpret_cast<float4*>(&ldsB[(nb + 16 * c) * X2S + c4 * 4]) = m;
        }
    }
    __syncthreads();                     // barrier 1: all x1 reads done; reuse ldsA for h1
    {
        float4* hrow = reinterpret_cast<float4*>(&ldsA[node * H1S + sub * 24]);
        #pragma unroll
        for (int j4 = 0; j4 < 6; ++j4) {
            float4 v;
            v.x = fmaxf(acc1[j4*4+0], 0.f);
            v.y = fmaxf(acc1[j4*4+1], 0.f);
            v.z = fmaxf(acc1[j4*4+2], 0.f);
            v.w = fmaxf(acc1[j4*4+3], 0.f);
            hrow[j4] = v;
        }
    }
    __syncthreads();                     // barrier 2: h1 visible

    // ---------- Phase 3: r1 = tanh(h1 @ w1b + b1b), j-slice of 16 ----------
    float r1v[16];
    {
        float acc[16];
        const float* b = b1b + sub * 16;
        #pragma unroll
        for (int j = 0; j < 16; ++j) acc[j] = b[j];
        const float4* hr = reinterpret_cast<const float4*>(&ldsA[node * H1S]);
        #pragma unroll 2
        for (int k4 = 0; k4 < 24; ++k4) {
            float4 x = hr[k4];
            const float* w0 = w1b + (k4 * 4) * 64 + sub * 16;
            #pragma unroll
            for (int j = 0; j < 16; ++j) acc[j] = fmaf(x.x, w0[j],       acc[j]);
            #pragma unroll
            for (int j = 0; j < 16; ++j) acc[j] = fmaf(x.y, w0[64 + j],  acc[j]);
            #pragma unroll
            for (int j = 0; j < 16; ++j) acc[j] = fmaf(x.z, w0[128 + j], acc[j]);
            #pragma unroll
            for (int j = 0; j < 16; ++j) acc[j] = fmaf(x.w, w0[192 + j], acc[j]);
        }
        #pragma unroll
        for (int j = 0; j < 16; ++j) r1v[j] = fast_tanh(acc[j]);
    }

    // ---------- Phase 4: h2 = relu(x2 @ w2a + b2a), j-slice of 16 ----------
    float h2v[16];
    {
        float acc[16];
        const float* b = b2a + sub * 16;
        #pragma unroll
        for (int j = 0; j < 16; ++j) acc[j] = b[j];
        const float4* xr = reinterpret_cast<const float4*>(&ldsB[node * X2S]);
        #pragma unroll 2
        for (int k4 = 0; k4 < 16; ++k4) {
            float4 x = xr[k4];
            const float* w0 = w2a + (k4 * 4) * 64 + sub * 16;
            #pragma unroll
            for (int j = 0; j < 16; ++j) acc[j] = fmaf(x.x, w0[j],       acc[j]);
            #pragma unroll
            for (int j = 0; j < 16; ++j) acc[j] = fmaf(x.y, w0[64 + j],  acc[j]);
            #pragma unroll
            for (int j = 0; j < 16; ++j) acc[j] = fmaf(x.z, w0[128 + j], acc[j]);
            #pragma unroll
            for (int j = 0; j < 16; ++j) acc[j] = fmaf(x.w, w0[192 + j], acc[j]);
        }
        #pragma unroll
        for (int j = 0; j < 16; ++j) h2v[j] = fmaxf(acc[j], 0.f);
    }
    __syncthreads();                     // barrier 3: all x2 reads done; reuse ldsB for h2
    {
        float4* hrow = reinterpret_cast<float4*>(&ldsB[node * X2S + sub * 16]);
        hrow[0] = make_float4(h2v[0],  h2v[1],  h2v[2],  h2v[3]);
        hrow[1] = make_float4(h2v[4],  h2v[5],  h2v[6],  h2v[7]);
        hrow[2] = make_float4(h2v[8],  h2v[9],  h2v[10], h2v[11]);
        hrow[3] = make_float4(h2v[12], h2v[13], h2v[14], h2v[15]);
    }
    __syncthreads();                     // barrier 4: h2 visible

    // ---------- Phase 5: r2 = tanh(h2 @ w2b + b2b), j-slice of 16 ----------
    float r2v[16];
    {
        float acc[16];
        const float* b = b2b + sub * 16;
        #pragma unroll
        for (int j = 0; j < 16; ++j) acc[j] = b[j];
        const float4* hr = reinterpret_cast<const float4*>(&ldsB[node * X2S]);
        #pragma unroll 2
        for (int k4 = 0; k4 < 16; ++k4) {
            float4 x = hr[k4];
            const float* w0 = w2b + (k4 * 4) * 64 + sub * 16;
            #pragma unroll
            for (int j = 0; j < 16; ++j) acc[j] = fmaf(x.x, w0[j],       acc[j]);
            #pragma unroll
            for (int j = 0; j < 16; ++j) acc[j] = fmaf(x.y, w0[64 + j],  acc[j]);
            #pragma unroll
            for (int j = 0; j < 16; ++j) acc[j] = fmaf(x.z, w0[128 + j], acc[j]);
            #pragma unroll
            for (int j = 0; j < 16; ++j) acc[j] = fmaf(x.w, w0[192 + j], acc[j]);
        }
        #pragma unroll
        for (int j = 0; j < 16; ++j) r2v[j] = fast_tanh(acc[j]);
    }

    // ---------- Phase 6: row L2 norm + write ----------
    float s = 0.f;
    #pragma unroll
    for (int j = 0; j < 16; ++j) s = fmaf(r1v[j], r1v[j], s);
    #pragma unroll
    for (int j = 0; j < 16; ++j) s = fmaf(r2v[j], r2v[j], s);
    ldsS[node * 4 + sub] = s;
    __syncthreads();                     // barrier 5
    float4 sv = reinterpret_cast<const float4*>(ldsS)[node];
    float rn = rsqrtf(sv.x + sv.y + sv.z + sv.w);

    float* orow = out + (size_t)(n0 + node) * 128;
    float4* o1 = reinterpret_cast<float4*>(orow + sub * 16);
    float4* o2 = reinterpret_cast<float4*>(orow + 64 + sub * 16);
    #pragma unroll
    for (int j4 = 0; j4 < 4; ++j4) {
        o1[j4] = make_float4(r1v[j4*4+0]*rn, r1v[j4*4+1]*rn, r1v[j4*4+2]*rn, r1v[j4*4+3]*rn);
        o2[j4] = make_float4(r2v[j4*4+0]*rn, r2v[j4*4+1]*rn, r2v[j4*4+2]*rn, r2v[j4*4+3]*rn);
    }
}

extern "C" void kernel_launch(void* const* d_in, const int* in_sizes, int n_in,
                              void* d_out, int out_size, void* d_ws, size_t ws_size,
                              hipStream_t stream) {
    const float* feat = (const float*)d_in[0];
    const float* hid  = (const float*)d_in[1];
    const float* mail = (const float*)d_in[2];
    const float* w1a  = (const float*)d_in[3];
    const float* b1a  = (const float*)d_in[4];
    const float* w1b  = (const float*)d_in[5];
    const float* b1b  = (const float*)d_in[6];
    const float* w2a  = (const float*)d_in[7];
    const float* b2a  = (const float*)d_in[8];
    const float* w2b  = (const float*)d_in[9];
    const float* b2b  = (const float*)d_in[10];
    float* out = (float*)d_out;

    const int N = in_sizes[0] / 64;          // 200000
    const int blocks = N / NB;               // 3125

    node_net_kernel<<<blocks, THREADS, 0, stream>>>(
        feat, hid, mail, w1a, b1a, w1b, b1b, w2a, b2a, w2b, b2b, out);
}